// Round 1
// baseline (705.771 us; speedup 1.0000x reference)
//
#include <hip/hip_runtime.h>

// GCN 3-layer encoder, fp32.
// Pipeline per call:
//  1) cnt[i] = #edges with col==i          (atomic count)
//  2) dinv[i] = rsqrt(cnt[i]+1)            (+1 = self-loop)
//  3) offs = exclusive_scan(cnt)           (3-kernel scan)
//  4) CSR fill: csr[pos] = row[e] grouped by col (atomic cursor)
//  5) per layer: h = A @ W (tiled fp32 GEMM), then wave-per-node gather:
//     out[i] = sum_{e in CSR[i]} h[src]*dinv[src]*dinv[i] + h[i]*dinv[i]^2 + b

#define K_DIM 128

// ---------------- preprocessing ----------------

__global__ void zero_i32(int* __restrict__ p, int n) {
    int i = blockIdx.x * 256 + threadIdx.x;
    if (i < n) p[i] = 0;
}

__global__ void count_deg(const int* __restrict__ col, int E, int* __restrict__ cnt) {
    int e = blockIdx.x * 256 + threadIdx.x;
    if (e < E) atomicAdd(&cnt[col[e]], 1);
}

__global__ void make_dinv(const int* __restrict__ cnt, float* __restrict__ dinv, int N) {
    int i = blockIdx.x * 256 + threadIdx.x;
    if (i < N) dinv[i] = rsqrtf((float)(cnt[i] + 1));
}

__global__ __launch_bounds__(256) void scan1(const int* __restrict__ cnt, int N,
                                             int* __restrict__ offs, int* __restrict__ bsum) {
    __shared__ int sh[256];
    int tid = threadIdx.x;
    int base = blockIdx.x * 1024;
    int v[4];
    int sum = 0;
#pragma unroll
    for (int j = 0; j < 4; ++j) {
        int i = base + tid * 4 + j;
        v[j] = (i < N) ? cnt[i] : 0;
        sum += v[j];
    }
    sh[tid] = sum;
    __syncthreads();
#pragma unroll
    for (int off = 1; off < 256; off <<= 1) {
        int t = (tid >= off) ? sh[tid - off] : 0;
        __syncthreads();
        sh[tid] += t;
        __syncthreads();
    }
    int run = (tid > 0) ? sh[tid - 1] : 0;
#pragma unroll
    for (int j = 0; j < 4; ++j) {
        int i = base + tid * 4 + j;
        if (i < N) offs[i] = run;
        run += v[j];
    }
    if (tid == 255) bsum[blockIdx.x] = sh[255];
}

__global__ void scan2(int* bsum, int nb) {
    if (threadIdx.x == 0 && blockIdx.x == 0) {
        int run = 0;
        for (int b = 0; b < nb; ++b) {
            int t = bsum[b];
            bsum[b] = run;
            run += t;
        }
    }
}

__global__ void scan3(int* __restrict__ offs, const int* __restrict__ bsum,
                      int* __restrict__ cursor, int N, int E) {
    int i = blockIdx.x * 256 + threadIdx.x;
    if (i < N) {
        int v = offs[i] + bsum[i >> 10];
        offs[i] = v;
        cursor[i] = v;
    }
    if (i == 0) offs[N] = E;
}

__global__ void fill_csr(const int* __restrict__ row, const int* __restrict__ col, int E,
                         int* __restrict__ cursor, int* __restrict__ csr) {
    int e = blockIdx.x * 256 + threadIdx.x;
    if (e < E) {
        int d = col[e];
        int pos = atomicAdd(&cursor[d], 1);
        csr[pos] = row[e];
    }
}

// ---------------- dense transform: out[M][NCOLS] = A[M][128] @ W[128][NCOLS] ----------------
// BM=128 rows/block, full N per block, BK=16. 256 threads, 8 x TN register tile.

template <int NCOLS>
__global__ __launch_bounds__(256) void gemm_fp32(const float* __restrict__ A,
                                                 const float* __restrict__ W,
                                                 float* __restrict__ out, int M) {
    constexpr int TN = NCOLS / 16;  // 8 (N=128) or 4 (N=64)
    constexpr int BK = 16;
    __shared__ __align__(16) float sA[BK][132];     // [k][row], padded: row stride 132*4=528B (16B mult)
    __shared__ __align__(16) float sW[BK][NCOLS];   // [k][n]

    const int tid = threadIdx.x;
    const int tx = tid & 15;
    const int ty = tid >> 4;
    const int row0 = blockIdx.x * 128;

    float acc[8][TN];
#pragma unroll
    for (int i = 0; i < 8; ++i)
#pragma unroll
        for (int j = 0; j < TN; ++j) acc[i][j] = 0.f;

    const int arow = tid >> 1;   // 0..127
    const int ahalf = tid & 1;   // which 8-float half of the 16-wide k-chunk
    const int grow = row0 + arow;
    const bool rowok = grow < M;

    for (int kc = 0; kc < K_DIM; kc += BK) {
        // global loads into regs
        float4 a0 = make_float4(0.f, 0.f, 0.f, 0.f), a1 = a0;
        if (rowok) {
            const float* ap = A + (size_t)grow * K_DIM + kc + ahalf * 8;
            a0 = *(const float4*)ap;
            a1 = *(const float4*)(ap + 4);
        }
        float4 w0, w1;
        const int wk = tid >> 4;   // 0..15
        const int wseg = tid & 15; // 0..15
        if constexpr (NCOLS == 128) {
            const float* wp = W + (size_t)(kc + wk) * NCOLS + wseg * 8;
            w0 = *(const float4*)wp;
            w1 = *(const float4*)(wp + 4);
        } else {
            const float* wp = W + (size_t)(kc + wk) * NCOLS + wseg * 4;
            w0 = *(const float4*)wp;
        }

        __syncthreads();  // previous tile fully consumed before overwrite

        // store A tile transposed: sA[k][row]
        {
            const int kb = ahalf * 8;
            sA[kb + 0][arow] = a0.x; sA[kb + 1][arow] = a0.y;
            sA[kb + 2][arow] = a0.z; sA[kb + 3][arow] = a0.w;
            sA[kb + 4][arow] = a1.x; sA[kb + 5][arow] = a1.y;
            sA[kb + 6][arow] = a1.z; sA[kb + 7][arow] = a1.w;
        }
        if constexpr (NCOLS == 128) {
            *(float4*)&sW[wk][wseg * 8] = w0;
            *(float4*)&sW[wk][wseg * 8 + 4] = w1;
        } else {
            *(float4*)&sW[wk][wseg * 4] = w0;
        }
        __syncthreads();

#pragma unroll
        for (int kk = 0; kk < BK; ++kk) {
            float4 x0 = *(const float4*)&sA[kk][ty * 8];
            float4 x1 = *(const float4*)&sA[kk][ty * 8 + 4];
            float xr[8] = {x0.x, x0.y, x0.z, x0.w, x1.x, x1.y, x1.z, x1.w};
            float wv[TN];
#pragma unroll
            for (int j = 0; j < TN; j += 4) {
                float4 w = *(const float4*)&sW[kk][tx * TN + j];
                wv[j] = w.x; wv[j + 1] = w.y; wv[j + 2] = w.z; wv[j + 3] = w.w;
            }
#pragma unroll
            for (int i = 0; i < 8; ++i)
#pragma unroll
                for (int j = 0; j < TN; ++j) acc[i][j] = fmaf(xr[i], wv[j], acc[i][j]);
        }
    }

#pragma unroll
    for (int i = 0; i < 8; ++i) {
        int r = row0 + ty * 8 + i;
        if (r < M) {
            float* op = out + (size_t)r * NCOLS + tx * TN;
#pragma unroll
            for (int j = 0; j < TN; j += 4) {
                *(float4*)(op + j) = make_float4(acc[i][j], acc[i][j + 1], acc[i][j + 2], acc[i][j + 3]);
            }
        }
    }
}

// ---------------- aggregation: wave per node, gather + register accumulate ----------------

template <int C, bool RELU>
__global__ __launch_bounds__(256) void agg_gather(const float* __restrict__ h,
                                                  const float* __restrict__ dinv,
                                                  const int* __restrict__ offs,
                                                  const int* __restrict__ csr,
                                                  const float* __restrict__ bias,
                                                  float* __restrict__ out, int N) {
    const int wid = (blockIdx.x * 256 + threadIdx.x) >> 6;  // node
    if (wid >= N) return;
    const int lane = threadIdx.x & 63;
    const int beg = offs[wid];
    const int end = offs[wid + 1];
    const float di = dinv[wid];

    if constexpr (C == 128) {
        const float2* __restrict__ hp = (const float2*)h;
        float ax = 0.f, ay = 0.f;
        int e = beg;
        for (; e + 2 <= end; e += 2) {
            int s0 = csr[e];
            int s1 = csr[e + 1];
            float w0 = dinv[s0] * di;
            float w1 = dinv[s1] * di;
            float2 v0 = hp[(size_t)s0 * 64 + lane];
            float2 v1 = hp[(size_t)s1 * 64 + lane];
            ax += v0.x * w0 + v1.x * w1;
            ay += v0.y * w0 + v1.y * w1;
        }
        if (e < end) {
            int s0 = csr[e];
            float w0 = dinv[s0] * di;
            float2 v0 = hp[(size_t)s0 * 64 + lane];
            ax += v0.x * w0;
            ay += v0.y * w0;
        }
        // self-loop
        {
            float2 vs = hp[(size_t)wid * 64 + lane];
            float sw = di * di;
            ax += vs.x * sw;
            ay += vs.y * sw;
        }
        float2 b = ((const float2*)bias)[lane];
        ax += b.x;
        ay += b.y;
        if (RELU) {
            ax = fmaxf(ax, 0.f);
            ay = fmaxf(ay, 0.f);
        }
        ((float2*)out)[(size_t)wid * 64 + lane] = make_float2(ax, ay);
    } else {  // C == 64
        float acc = 0.f;
        int e = beg;
        for (; e + 2 <= end; e += 2) {
            int s0 = csr[e];
            int s1 = csr[e + 1];
            float w0 = dinv[s0] * di;
            float w1 = dinv[s1] * di;
            acc += h[(size_t)s0 * 64 + lane] * w0 + h[(size_t)s1 * 64 + lane] * w1;
        }
        if (e < end) {
            int s0 = csr[e];
            acc += h[(size_t)s0 * 64 + lane] * (dinv[s0] * di);
        }
        acc += h[(size_t)wid * 64 + lane] * (di * di);
        acc += bias[lane];
        if (RELU) acc = fmaxf(acc, 0.f);
        out[(size_t)wid * 64 + lane] = acc;
    }
}

// ---------------- launch ----------------

extern "C" void kernel_launch(void* const* d_in, const int* in_sizes, int n_in,
                              void* d_out, int out_size, void* d_ws, size_t ws_size,
                              hipStream_t stream) {
    const float* x  = (const float*)d_in[0];
    const int*   ei = (const int*)d_in[1];
    const float* W1 = (const float*)d_in[2];
    const float* b1 = (const float*)d_in[3];
    const float* W2 = (const float*)d_in[4];
    const float* b2 = (const float*)d_in[5];
    const float* W3 = (const float*)d_in[6];
    const float* b3 = (const float*)d_in[7];

    const int N = in_sizes[0] / 128;
    const int E = in_sizes[1] / 2;
    const int* row = ei;       // sources
    const int* col = ei + E;   // targets

    // workspace bump allocator (256B aligned)
    char* p = (char*)d_ws;
    auto alloc = [&](size_t bytes) {
        char* r = p;
        p += (bytes + 255) & ~(size_t)255;
        return r;
    };
    int*   cnt    = (int*)alloc((size_t)N * 4);
    int*   offs   = (int*)alloc((size_t)(N + 1) * 4);
    int*   cursor = (int*)alloc((size_t)N * 4);
    float* dinv   = (float*)alloc((size_t)N * 4);
    int*   bsum   = (int*)alloc(1024 * 4);
    int*   csr    = (int*)alloc((size_t)E * 4);
    float* hA     = (float*)alloc((size_t)N * 128 * 4);
    float* hB     = (float*)alloc((size_t)N * 128 * 4);

    const int gN = (N + 255) / 256;
    const int gE = (E + 255) / 256;
    const int nb = (N + 1023) / 1024;

    // preprocessing
    zero_i32<<<gN, 256, 0, stream>>>(cnt, N);
    count_deg<<<gE, 256, 0, stream>>>(col, E, cnt);
    make_dinv<<<gN, 256, 0, stream>>>(cnt, dinv, N);
    scan1<<<nb, 256, 0, stream>>>(cnt, N, offs, bsum);
    scan2<<<1, 64, 0, stream>>>(bsum, nb);
    scan3<<<gN, 256, 0, stream>>>(offs, bsum, cursor, N, E);
    fill_csr<<<gE, 256, 0, stream>>>(row, col, E, cursor, csr);

    const int gGemm = (N + 127) / 128;
    const int gAgg = (N + 3) / 4;  // 4 waves (nodes) per 256-thread block

    // layer 1: h = relu(S (x W1) + b1)
    gemm_fp32<128><<<gGemm, 256, 0, stream>>>(x, W1, hA, N);
    agg_gather<128, true><<<gAgg, 256, 0, stream>>>(hA, dinv, offs, csr, b1, hB, N);

    // layer 2
    gemm_fp32<128><<<gGemm, 256, 0, stream>>>(hB, W2, hA, N);
    agg_gather<128, true><<<gAgg, 256, 0, stream>>>(hA, dinv, offs, csr, b2, hB, N);

    // layer 3 (no relu), N=64 out
    gemm_fp32<64><<<gGemm, 256, 0, stream>>>(hB, W3, hA, N);
    agg_gather<64, false><<<gAgg, 256, 0, stream>>>(hA, dinv, offs, csr, b3, (float*)d_out, N);
}

// Round 2
// 538.601 us; speedup vs baseline: 1.3104x; 1.3104x over previous
//
#include <hip/hip_runtime.h>

// GCN 3-layer encoder, fp32.
// CSR build via 2-level counting sort (no global atomics):
//  A) hist_pass:   per-block LDS histogram over coarse buckets (dst>>7),
//                  stored bucket-major histG[b*B1 + blk]
//  B) exclusive scan of histG (block scan + single-block scan + fixup)
//  C) scatter_pass: edges -> ebuf packed (src<<7 | dst&127), bucket-grouped,
//                  positions from LDS cursors seeded by scanned histG
//  D) build_csr:   block per bucket: LDS 128-bin count + scan ->
//                  offs[], dinv[], then scatter csr[] within 8KB window
// Then per layer: h = A @ W (tiled fp32 GEMM), wave-per-node gather:
//     out[i] = sum_{e in CSR[i]} h[src]*dinv[src]*dinv[i] + h[i]*dinv[i]^2 + b

#define K_DIM 128
#define CHUNK 8192
#define NBMAX 1024  // max coarse buckets -> supports N <= 131072

// ---------------- preprocessing: counting-sort CSR build ----------------

__global__ __launch_bounds__(256) void hist_pass(const int* __restrict__ col, int E,
                                                 int NB, int B1, int* __restrict__ histG) {
    __shared__ int h[NBMAX];
    const int tid = threadIdx.x;
    for (int i = tid; i < NB; i += 256) h[i] = 0;
    __syncthreads();
    const int base = blockIdx.x * CHUNK;
    const int end = min(base + CHUNK, E);
    for (int e = base + tid; e < end; e += 256) atomicAdd(&h[col[e] >> 7], 1);
    __syncthreads();
    for (int i = tid; i < NB; i += 256) histG[(size_t)i * B1 + blockIdx.x] = h[i];
}

// block-level exclusive scan (1024 elems/block), partials to bsum
__global__ __launch_bounds__(256) void scan_blocks(int* __restrict__ data, int n,
                                                   int* __restrict__ bsum) {
    __shared__ int sh[256];
    const int tid = threadIdx.x;
    const int base = blockIdx.x * 1024;
    int v[4];
    int sum = 0;
#pragma unroll
    for (int j = 0; j < 4; ++j) {
        int i = base + tid * 4 + j;
        v[j] = (i < n) ? data[i] : 0;
        sum += v[j];
    }
    sh[tid] = sum;
    __syncthreads();
#pragma unroll
    for (int off = 1; off < 256; off <<= 1) {
        int t = (tid >= off) ? sh[tid - off] : 0;
        __syncthreads();
        sh[tid] += t;
        __syncthreads();
    }
    int run = (tid > 0) ? sh[tid - 1] : 0;
#pragma unroll
    for (int j = 0; j < 4; ++j) {
        int i = base + tid * 4 + j;
        if (i < n) data[i] = run;
        run += v[j];
    }
    if (tid == 255) bsum[blockIdx.x] = sh[255];
}

// single-block exclusive scan for n <= 1024
__global__ __launch_bounds__(256) void scan_single(int* __restrict__ data, int n) {
    __shared__ int sh[256];
    const int tid = threadIdx.x;
    int v[4];
    int sum = 0;
#pragma unroll
    for (int j = 0; j < 4; ++j) {
        int i = tid * 4 + j;
        v[j] = (i < n) ? data[i] : 0;
        sum += v[j];
    }
    sh[tid] = sum;
    __syncthreads();
#pragma unroll
    for (int off = 1; off < 256; off <<= 1) {
        int t = (tid >= off) ? sh[tid - off] : 0;
        __syncthreads();
        sh[tid] += t;
        __syncthreads();
    }
    int run = (tid > 0) ? sh[tid - 1] : 0;
#pragma unroll
    for (int j = 0; j < 4; ++j) {
        int i = tid * 4 + j;
        if (i < n) data[i] = run;
        run += v[j];
    }
}

__global__ void add_bsum(int* __restrict__ data, const int* __restrict__ bsum, int n) {
    int i = blockIdx.x * 256 + threadIdx.x;
    if (i < n) data[i] += bsum[i >> 10];
}

__global__ __launch_bounds__(256) void scatter_pass(const int* __restrict__ row,
                                                    const int* __restrict__ col, int E,
                                                    int NB, int B1,
                                                    const int* __restrict__ histG,
                                                    int* __restrict__ ebuf) {
    __shared__ int cur[NBMAX];
    const int tid = threadIdx.x;
    for (int i = tid; i < NB; i += 256) cur[i] = histG[(size_t)i * B1 + blockIdx.x];
    __syncthreads();
    const int base = blockIdx.x * CHUNK;
    const int end = min(base + CHUNK, E);
    for (int e = base + tid; e < end; e += 256) {
        int d = col[e];
        int s = row[e];
        int pos = atomicAdd(&cur[d >> 7], 1);
        ebuf[pos] = (s << 7) | (d & 127);
    }
}

__global__ __launch_bounds__(256) void build_csr(const int* __restrict__ ebuf,
                                                 const int* __restrict__ histG,
                                                 int NB, int B1, int N, int E,
                                                 int* __restrict__ offs,
                                                 float* __restrict__ dinv,
                                                 int* __restrict__ csr) {
    __shared__ int cnt[128];
    __shared__ int scn[128];
    __shared__ int curL[128];
    const int tid = threadIdx.x;
    const int b = blockIdx.x;
    const int S = histG[(size_t)b * B1];
    const int T = (b + 1 < NB) ? histG[(size_t)(b + 1) * B1] : E;

    if (tid < 128) cnt[tid] = 0;
    __syncthreads();
    for (int i = S + tid; i < T; i += 256) atomicAdd(&cnt[ebuf[i] & 127], 1);
    __syncthreads();
    // inclusive Hillis-Steele over 128 (all threads hit barriers)
    if (tid < 128) scn[tid] = cnt[tid];
    __syncthreads();
#pragma unroll
    for (int off = 1; off < 128; off <<= 1) {
        int t = (tid < 128 && tid >= off) ? scn[tid - off] : 0;
        __syncthreads();
        if (tid < 128) scn[tid] += t;
        __syncthreads();
    }
    if (tid < 128) {
        int exc = (tid > 0) ? scn[tid - 1] : 0;
        int node = b * 128 + tid;
        if (node < N) {
            offs[node] = S + exc;
            dinv[node] = rsqrtf((float)(cnt[tid] + 1));
        }
        curL[tid] = S + exc;
    }
    if (b == 0 && tid == 0) offs[N] = E;
    __syncthreads();
    for (int i = S + tid; i < T; i += 256) {
        int p = ebuf[i];
        int pos = atomicAdd(&curL[p & 127], 1);
        csr[pos] = p >> 7;
    }
}

// ---------------- dense transform: out[M][NCOLS] = A[M][128] @ W[128][NCOLS] ----------------

template <int NCOLS>
__global__ __launch_bounds__(256) void gemm_fp32(const float* __restrict__ A,
                                                 const float* __restrict__ W,
                                                 float* __restrict__ out, int M) {
    constexpr int TN = NCOLS / 16;  // 8 (N=128) or 4 (N=64)
    constexpr int BK = 16;
    __shared__ __align__(16) float sA[BK][132];
    __shared__ __align__(16) float sW[BK][NCOLS];

    const int tid = threadIdx.x;
    const int tx = tid & 15;
    const int ty = tid >> 4;
    const int row0 = blockIdx.x * 128;

    float acc[8][TN];
#pragma unroll
    for (int i = 0; i < 8; ++i)
#pragma unroll
        for (int j = 0; j < TN; ++j) acc[i][j] = 0.f;

    const int arow = tid >> 1;
    const int ahalf = tid & 1;
    const int grow = row0 + arow;
    const bool rowok = grow < M;

    for (int kc = 0; kc < K_DIM; kc += BK) {
        float4 a0 = make_float4(0.f, 0.f, 0.f, 0.f), a1 = a0;
        if (rowok) {
            const float* ap = A + (size_t)grow * K_DIM + kc + ahalf * 8;
            a0 = *(const float4*)ap;
            a1 = *(const float4*)(ap + 4);
        }
        float4 w0, w1;
        const int wk = tid >> 4;
        const int wseg = tid & 15;
        if constexpr (NCOLS == 128) {
            const float* wp = W + (size_t)(kc + wk) * NCOLS + wseg * 8;
            w0 = *(const float4*)wp;
            w1 = *(const float4*)(wp + 4);
        } else {
            const float* wp = W + (size_t)(kc + wk) * NCOLS + wseg * 4;
            w0 = *(const float4*)wp;
        }

        __syncthreads();

        {
            const int kb = ahalf * 8;
            sA[kb + 0][arow] = a0.x; sA[kb + 1][arow] = a0.y;
            sA[kb + 2][arow] = a0.z; sA[kb + 3][arow] = a0.w;
            sA[kb + 4][arow] = a1.x; sA[kb + 5][arow] = a1.y;
            sA[kb + 6][arow] = a1.z; sA[kb + 7][arow] = a1.w;
        }
        if constexpr (NCOLS == 128) {
            *(float4*)&sW[wk][wseg * 8] = w0;
            *(float4*)&sW[wk][wseg * 8 + 4] = w1;
        } else {
            *(float4*)&sW[wk][wseg * 4] = w0;
        }
        __syncthreads();

#pragma unroll
        for (int kk = 0; kk < BK; ++kk) {
            float4 x0 = *(const float4*)&sA[kk][ty * 8];
            float4 x1 = *(const float4*)&sA[kk][ty * 8 + 4];
            float xr[8] = {x0.x, x0.y, x0.z, x0.w, x1.x, x1.y, x1.z, x1.w};
            float wv[TN];
#pragma unroll
            for (int j = 0; j < TN; j += 4) {
                float4 w = *(const float4*)&sW[kk][tx * TN + j];
                wv[j] = w.x; wv[j + 1] = w.y; wv[j + 2] = w.z; wv[j + 3] = w.w;
            }
#pragma unroll
            for (int i = 0; i < 8; ++i)
#pragma unroll
                for (int j = 0; j < TN; ++j) acc[i][j] = fmaf(xr[i], wv[j], acc[i][j]);
        }
    }

#pragma unroll
    for (int i = 0; i < 8; ++i) {
        int r = row0 + ty * 8 + i;
        if (r < M) {
            float* op = out + (size_t)r * NCOLS + tx * TN;
#pragma unroll
            for (int j = 0; j < TN; j += 4) {
                *(float4*)(op + j) = make_float4(acc[i][j], acc[i][j + 1], acc[i][j + 2], acc[i][j + 3]);
            }
        }
    }
}

// ---------------- aggregation: wave per node, gather + register accumulate ----------------

template <int C, bool RELU>
__global__ __launch_bounds__(256) void agg_gather(const float* __restrict__ h,
                                                  const float* __restrict__ dinv,
                                                  const int* __restrict__ offs,
                                                  const int* __restrict__ csr,
                                                  const float* __restrict__ bias,
                                                  float* __restrict__ out, int N) {
    const int wid = (blockIdx.x * 256 + threadIdx.x) >> 6;
    if (wid >= N) return;
    const int lane = threadIdx.x & 63;
    const int beg = offs[wid];
    const int end = offs[wid + 1];
    const float di = dinv[wid];

    if constexpr (C == 128) {
        const float2* __restrict__ hp = (const float2*)h;
        float ax = 0.f, ay = 0.f;
        int e = beg;
        for (; e + 2 <= end; e += 2) {
            int s0 = csr[e];
            int s1 = csr[e + 1];
            float w0 = dinv[s0] * di;
            float w1 = dinv[s1] * di;
            float2 v0 = hp[(size_t)s0 * 64 + lane];
            float2 v1 = hp[(size_t)s1 * 64 + lane];
            ax += v0.x * w0 + v1.x * w1;
            ay += v0.y * w0 + v1.y * w1;
        }
        if (e < end) {
            int s0 = csr[e];
            float w0 = dinv[s0] * di;
            float2 v0 = hp[(size_t)s0 * 64 + lane];
            ax += v0.x * w0;
            ay += v0.y * w0;
        }
        {
            float2 vs = hp[(size_t)wid * 64 + lane];
            float sw = di * di;
            ax += vs.x * sw;
            ay += vs.y * sw;
        }
        float2 b = ((const float2*)bias)[lane];
        ax += b.x;
        ay += b.y;
        if (RELU) {
            ax = fmaxf(ax, 0.f);
            ay = fmaxf(ay, 0.f);
        }
        ((float2*)out)[(size_t)wid * 64 + lane] = make_float2(ax, ay);
    } else {
        float acc = 0.f;
        int e = beg;
        for (; e + 2 <= end; e += 2) {
            int s0 = csr[e];
            int s1 = csr[e + 1];
            float w0 = dinv[s0] * di;
            float w1 = dinv[s1] * di;
            acc += h[(size_t)s0 * 64 + lane] * w0 + h[(size_t)s1 * 64 + lane] * w1;
        }
        if (e < end) {
            int s0 = csr[e];
            acc += h[(size_t)s0 * 64 + lane] * (dinv[s0] * di);
        }
        acc += h[(size_t)wid * 64 + lane] * (di * di);
        acc += bias[lane];
        if (RELU) acc = fmaxf(acc, 0.f);
        out[(size_t)wid * 64 + lane] = acc;
    }
}

// ---------------- launch ----------------

extern "C" void kernel_launch(void* const* d_in, const int* in_sizes, int n_in,
                              void* d_out, int out_size, void* d_ws, size_t ws_size,
                              hipStream_t stream) {
    const float* x  = (const float*)d_in[0];
    const int*   ei = (const int*)d_in[1];
    const float* W1 = (const float*)d_in[2];
    const float* b1 = (const float*)d_in[3];
    const float* W2 = (const float*)d_in[4];
    const float* b2 = (const float*)d_in[5];
    const float* W3 = (const float*)d_in[6];
    const float* b3 = (const float*)d_in[7];

    const int N = in_sizes[0] / 128;
    const int E = in_sizes[1] / 2;
    const int* row = ei;       // sources
    const int* col = ei + E;   // targets

    const int NB = (N + 127) >> 7;          // coarse buckets (128 nodes each)
    const int B1 = (E + CHUNK - 1) / CHUNK; // chunk blocks
    const int NBB1 = NB * B1;

    // workspace bump allocator (256B aligned)
    char* p = (char*)d_ws;
    auto alloc = [&](size_t bytes) {
        char* r = p;
        p += (bytes + 255) & ~(size_t)255;
        return r;
    };
    int*   offs  = (int*)alloc((size_t)(N + 1) * 4);
    float* dinv  = (float*)alloc((size_t)N * 4);
    int*   histG = (int*)alloc((size_t)NBB1 * 4);
    int*   bsum  = (int*)alloc(1024 * 4);
    int*   ebuf  = (int*)alloc((size_t)E * 4);
    int*   csr   = (int*)alloc((size_t)E * 4);
    float* hA    = (float*)alloc((size_t)N * 128 * 4);
    float* hB    = (float*)alloc((size_t)N * 128 * 4);

    const int nsb = (NBB1 + 1023) / 1024;  // scan blocks (<= 1024)

    // CSR build
    hist_pass<<<B1, 256, 0, stream>>>(col, E, NB, B1, histG);
    scan_blocks<<<nsb, 256, 0, stream>>>(histG, NBB1, bsum);
    scan_single<<<1, 256, 0, stream>>>(bsum, nsb);
    add_bsum<<<(NBB1 + 255) / 256, 256, 0, stream>>>(histG, bsum, NBB1);
    scatter_pass<<<B1, 256, 0, stream>>>(row, col, E, NB, B1, histG, ebuf);
    build_csr<<<NB, 256, 0, stream>>>(ebuf, histG, NB, B1, N, E, offs, dinv, csr);

    const int gGemm = (N + 127) / 128;
    const int gAgg = (N + 3) / 4;

    // layer 1: h = relu(S (x W1) + b1)
    gemm_fp32<128><<<gGemm, 256, 0, stream>>>(x, W1, hA, N);
    agg_gather<128, true><<<gAgg, 256, 0, stream>>>(hA, dinv, offs, csr, b1, hB, N);

    // layer 2
    gemm_fp32<128><<<gGemm, 256, 0, stream>>>(hB, W2, hA, N);
    agg_gather<128, true><<<gAgg, 256, 0, stream>>>(hA, dinv, offs, csr, b2, hB, N);

    // layer 3 (no relu), N=64 out
    gemm_fp32<64><<<gGemm, 256, 0, stream>>>(hB, W3, hA, N);
    agg_gather<64, false><<<gAgg, 256, 0, stream>>>(hA, dinv, offs, csr, b3, (float*)d_out, N);
}

// Round 3
// 388.524 us; speedup vs baseline: 1.8165x; 1.3863x over previous
//
#include <hip/hip_runtime.h>
#include <hip/hip_fp16.h>

// GCN 3-layer encoder. fp32 GEMM (fp16 output), fp16 gather w/ fp32 accumulate.
// CSR build via 2-level counting sort (no global atomics) — see R2.
// Per layer: h16 = A @ W (fp32 acc, fp16 store); wave-per-node gather:
//     out[i] = sum_{e in CSR[i]} h16[src]*dinv[src]*dinv[i] + h16[i]*dinv[i]^2 + b

#define K_DIM 128
#define CHUNK 8192
#define NBMAX 1024  // max coarse buckets -> supports N <= 131072

// ---------------- preprocessing: counting-sort CSR build ----------------

__global__ __launch_bounds__(256) void hist_pass(const int* __restrict__ col, int E,
                                                 int NB, int B1, int* __restrict__ histG) {
    __shared__ int h[NBMAX];
    const int tid = threadIdx.x;
    for (int i = tid; i < NB; i += 256) h[i] = 0;
    __syncthreads();
    const int base = blockIdx.x * CHUNK;
    const int end = min(base + CHUNK, E);
    for (int e = base + tid; e < end; e += 256) atomicAdd(&h[col[e] >> 7], 1);
    __syncthreads();
    for (int i = tid; i < NB; i += 256) histG[(size_t)i * B1 + blockIdx.x] = h[i];
}

__global__ __launch_bounds__(256) void scan_blocks(int* __restrict__ data, int n,
                                                   int* __restrict__ bsum) {
    __shared__ int sh[256];
    const int tid = threadIdx.x;
    const int base = blockIdx.x * 1024;
    int v[4];
    int sum = 0;
#pragma unroll
    for (int j = 0; j < 4; ++j) {
        int i = base + tid * 4 + j;
        v[j] = (i < n) ? data[i] : 0;
        sum += v[j];
    }
    sh[tid] = sum;
    __syncthreads();
#pragma unroll
    for (int off = 1; off < 256; off <<= 1) {
        int t = (tid >= off) ? sh[tid - off] : 0;
        __syncthreads();
        sh[tid] += t;
        __syncthreads();
    }
    int run = (tid > 0) ? sh[tid - 1] : 0;
#pragma unroll
    for (int j = 0; j < 4; ++j) {
        int i = base + tid * 4 + j;
        if (i < n) data[i] = run;
        run += v[j];
    }
    if (tid == 255) bsum[blockIdx.x] = sh[255];
}

__global__ __launch_bounds__(256) void scan_single(int* __restrict__ data, int n) {
    __shared__ int sh[256];
    const int tid = threadIdx.x;
    int v[4];
    int sum = 0;
#pragma unroll
    for (int j = 0; j < 4; ++j) {
        int i = tid * 4 + j;
        v[j] = (i < n) ? data[i] : 0;
        sum += v[j];
    }
    sh[tid] = sum;
    __syncthreads();
#pragma unroll
    for (int off = 1; off < 256; off <<= 1) {
        int t = (tid >= off) ? sh[tid - off] : 0;
        __syncthreads();
        sh[tid] += t;
        __syncthreads();
    }
    int run = (tid > 0) ? sh[tid - 1] : 0;
#pragma unroll
    for (int j = 0; j < 4; ++j) {
        int i = tid * 4 + j;
        if (i < n) data[i] = run;
        run += v[j];
    }
}

__global__ void add_bsum(int* __restrict__ data, const int* __restrict__ bsum, int n) {
    int i = blockIdx.x * 256 + threadIdx.x;
    if (i < n) data[i] += bsum[i >> 10];
}

__global__ __launch_bounds__(256) void scatter_pass(const int* __restrict__ row,
                                                    const int* __restrict__ col, int E,
                                                    int NB, int B1,
                                                    const int* __restrict__ histG,
                                                    int* __restrict__ ebuf) {
    __shared__ int cur[NBMAX];
    const int tid = threadIdx.x;
    for (int i = tid; i < NB; i += 256) cur[i] = histG[(size_t)i * B1 + blockIdx.x];
    __syncthreads();
    const int base = blockIdx.x * CHUNK;
    const int end = min(base + CHUNK, E);
    for (int e = base + tid; e < end; e += 256) {
        int d = col[e];
        int s = row[e];
        int pos = atomicAdd(&cur[d >> 7], 1);
        ebuf[pos] = (s << 7) | (d & 127);
    }
}

__global__ __launch_bounds__(256) void build_csr(const int* __restrict__ ebuf,
                                                 const int* __restrict__ histG,
                                                 int NB, int B1, int N, int E,
                                                 int* __restrict__ offs,
                                                 float* __restrict__ dinv,
                                                 int* __restrict__ csr) {
    __shared__ int cnt[128];
    __shared__ int scn[128];
    __shared__ int curL[128];
    const int tid = threadIdx.x;
    const int b = blockIdx.x;
    const int S = histG[(size_t)b * B1];
    const int T = (b + 1 < NB) ? histG[(size_t)(b + 1) * B1] : E;

    if (tid < 128) cnt[tid] = 0;
    __syncthreads();
    for (int i = S + tid; i < T; i += 256) atomicAdd(&cnt[ebuf[i] & 127], 1);
    __syncthreads();
    if (tid < 128) scn[tid] = cnt[tid];
    __syncthreads();
#pragma unroll
    for (int off = 1; off < 128; off <<= 1) {
        int t = (tid < 128 && tid >= off) ? scn[tid - off] : 0;
        __syncthreads();
        if (tid < 128) scn[tid] += t;
        __syncthreads();
    }
    if (tid < 128) {
        int exc = (tid > 0) ? scn[tid - 1] : 0;
        int node = b * 128 + tid;
        if (node < N) {
            offs[node] = S + exc;
            dinv[node] = rsqrtf((float)(cnt[tid] + 1));
        }
        curL[tid] = S + exc;
    }
    if (b == 0 && tid == 0) offs[N] = E;
    __syncthreads();
    for (int i = S + tid; i < T; i += 256) {
        int p = ebuf[i];
        int pos = atomicAdd(&curL[p & 127], 1);
        csr[pos] = p >> 7;
    }
}

// ------------- dense transform: out16[M][NCOLS] = A[M][128] @ W[128][NCOLS] -------------
// fp32 loads + fp32 FMA accumulate, fp16 converted store.

template <int NCOLS>
__global__ __launch_bounds__(256) void gemm_fp32_h(const float* __restrict__ A,
                                                   const float* __restrict__ W,
                                                   __half* __restrict__ out, int M) {
    constexpr int TN = NCOLS / 16;  // 8 (N=128) or 4 (N=64)
    constexpr int BK = 16;
    __shared__ __align__(16) float sA[BK][132];
    __shared__ __align__(16) float sW[BK][NCOLS];

    const int tid = threadIdx.x;
    const int tx = tid & 15;
    const int ty = tid >> 4;
    const int row0 = blockIdx.x * 128;

    float acc[8][TN];
#pragma unroll
    for (int i = 0; i < 8; ++i)
#pragma unroll
        for (int j = 0; j < TN; ++j) acc[i][j] = 0.f;

    const int arow = tid >> 1;
    const int ahalf = tid & 1;
    const int grow = row0 + arow;
    const bool rowok = grow < M;

    for (int kc = 0; kc < K_DIM; kc += BK) {
        float4 a0 = make_float4(0.f, 0.f, 0.f, 0.f), a1 = a0;
        if (rowok) {
            const float* ap = A + (size_t)grow * K_DIM + kc + ahalf * 8;
            a0 = *(const float4*)ap;
            a1 = *(const float4*)(ap + 4);
        }
        float4 w0, w1;
        const int wk = tid >> 4;
        const int wseg = tid & 15;
        if constexpr (NCOLS == 128) {
            const float* wp = W + (size_t)(kc + wk) * NCOLS + wseg * 8;
            w0 = *(const float4*)wp;
            w1 = *(const float4*)(wp + 4);
        } else {
            const float* wp = W + (size_t)(kc + wk) * NCOLS + wseg * 4;
            w0 = *(const float4*)wp;
        }

        __syncthreads();

        {
            const int kb = ahalf * 8;
            sA[kb + 0][arow] = a0.x; sA[kb + 1][arow] = a0.y;
            sA[kb + 2][arow] = a0.z; sA[kb + 3][arow] = a0.w;
            sA[kb + 4][arow] = a1.x; sA[kb + 5][arow] = a1.y;
            sA[kb + 6][arow] = a1.z; sA[kb + 7][arow] = a1.w;
        }
        if constexpr (NCOLS == 128) {
            *(float4*)&sW[wk][wseg * 8] = w0;
            *(float4*)&sW[wk][wseg * 8 + 4] = w1;
        } else {
            *(float4*)&sW[wk][wseg * 4] = w0;
        }
        __syncthreads();

#pragma unroll
        for (int kk = 0; kk < BK; ++kk) {
            float4 x0 = *(const float4*)&sA[kk][ty * 8];
            float4 x1 = *(const float4*)&sA[kk][ty * 8 + 4];
            float xr[8] = {x0.x, x0.y, x0.z, x0.w, x1.x, x1.y, x1.z, x1.w};
            float wv[TN];
#pragma unroll
            for (int j = 0; j < TN; j += 4) {
                float4 w = *(const float4*)&sW[kk][tx * TN + j];
                wv[j] = w.x; wv[j + 1] = w.y; wv[j + 2] = w.z; wv[j + 3] = w.w;
            }
#pragma unroll
            for (int i = 0; i < 8; ++i)
#pragma unroll
                for (int j = 0; j < TN; ++j) acc[i][j] = fmaf(xr[i], wv[j], acc[i][j]);
        }
    }

#pragma unroll
    for (int i = 0; i < 8; ++i) {
        int r = row0 + ty * 8 + i;
        if (r < M) {
            __half* op = out + (size_t)r * NCOLS + tx * TN;
            if constexpr (NCOLS == 128) {
                __half2 o[4];
#pragma unroll
                for (int j = 0; j < 4; ++j)
                    o[j] = __float22half2_rn(make_float2(acc[i][2 * j], acc[i][2 * j + 1]));
                *(float4*)op = *(const float4*)o;  // 16B store of 8 halves
            } else {
                __half2 o[2];
#pragma unroll
                for (int j = 0; j < 2; ++j)
                    o[j] = __float22half2_rn(make_float2(acc[i][2 * j], acc[i][2 * j + 1]));
                *(float2*)op = *(const float2*)o;  // 8B store of 4 halves
            }
        }
    }
}

// ---------------- aggregation: wave per node, fp16 gather + fp32 accumulate ----------------

// C=128: lane covers channels (2*lane, 2*lane+1); 4 edges in flight.
template <bool RELU>
__global__ __launch_bounds__(256) void agg128(const __half* __restrict__ h,
                                              const float* __restrict__ dinv,
                                              const int* __restrict__ offs,
                                              const int* __restrict__ csr,
                                              const float* __restrict__ bias,
                                              float* __restrict__ out, int N) {
    const int wid = (blockIdx.x * 256 + threadIdx.x) >> 6;
    if (wid >= N) return;
    const int lane = threadIdx.x & 63;
    const int beg = offs[wid];
    const int end = offs[wid + 1];
    const float di = dinv[wid];
    const __half2* __restrict__ hp = (const __half2*)h;  // row = 64 half2

    float ax = 0.f, ay = 0.f;
    int e = beg;
    for (; e + 4 <= end; e += 4) {
        int s0 = csr[e], s1 = csr[e + 1], s2 = csr[e + 2], s3 = csr[e + 3];
        float w0 = dinv[s0] * di, w1 = dinv[s1] * di, w2 = dinv[s2] * di, w3 = dinv[s3] * di;
        float2 v0 = __half22float2(hp[(size_t)s0 * 64 + lane]);
        float2 v1 = __half22float2(hp[(size_t)s1 * 64 + lane]);
        float2 v2 = __half22float2(hp[(size_t)s2 * 64 + lane]);
        float2 v3 = __half22float2(hp[(size_t)s3 * 64 + lane]);
        ax += v0.x * w0 + v1.x * w1 + v2.x * w2 + v3.x * w3;
        ay += v0.y * w0 + v1.y * w1 + v2.y * w2 + v3.y * w3;
    }
    for (; e < end; ++e) {
        int s0 = csr[e];
        float w0 = dinv[s0] * di;
        float2 v0 = __half22float2(hp[(size_t)s0 * 64 + lane]);
        ax += v0.x * w0;
        ay += v0.y * w0;
    }
    {
        float2 vs = __half22float2(hp[(size_t)wid * 64 + lane]);
        float sw = di * di;
        ax += vs.x * sw;
        ay += vs.y * sw;
    }
    float2 b = ((const float2*)bias)[lane];
    ax += b.x;
    ay += b.y;
    if (RELU) {
        ax = fmaxf(ax, 0.f);
        ay = fmaxf(ay, 0.f);
    }
    ((float2*)out)[(size_t)wid * 64 + lane] = make_float2(ax, ay);
}

// C=64: half-wave per edge (lanes 0-31 edge e, lanes 32-63 edge e+1), 2 pairs unrolled.
__global__ __launch_bounds__(256) void agg64(const __half* __restrict__ h,
                                             const float* __restrict__ dinv,
                                             const int* __restrict__ offs,
                                             const int* __restrict__ csr,
                                             const float* __restrict__ bias,
                                             float* __restrict__ out, int N) {
    const int wid = (blockIdx.x * 256 + threadIdx.x) >> 6;
    if (wid >= N) return;
    const int lane = threadIdx.x & 63;
    const int ch = lane & 31;       // half2 index within row (row = 32 half2)
    const int sub = lane >> 5;      // 0 or 1: which edge of the pair
    const int beg = offs[wid];
    const int end = offs[wid + 1];
    const float di = dinv[wid];
    const __half2* __restrict__ hp = (const __half2*)h;

    float ax = 0.f, ay = 0.f;
    int e = beg;
    for (; e + 4 <= end; e += 4) {
        int i0 = e + sub;
        int i1 = e + 2 + sub;
        int s0 = csr[i0], s1 = csr[i1];
        float w0 = dinv[s0] * di, w1 = dinv[s1] * di;
        float2 v0 = __half22float2(hp[(size_t)s0 * 32 + ch]);
        float2 v1 = __half22float2(hp[(size_t)s1 * 32 + ch]);
        ax += v0.x * w0 + v1.x * w1;
        ay += v0.y * w0 + v1.y * w1;
    }
    for (int i = e + sub; i < end; i += 2) {
        int s0 = csr[i];
        float w0 = dinv[s0] * di;
        float2 v0 = __half22float2(hp[(size_t)s0 * 32 + ch]);
        ax += v0.x * w0;
        ay += v0.y * w0;
    }
    // combine the two half-wave partials (channels align: lane ^ 32 has same ch)
    ax += __shfl_xor(ax, 32);
    ay += __shfl_xor(ay, 32);
    // self-loop + bias (computed redundantly on both halves)
    {
        float2 vs = __half22float2(hp[(size_t)wid * 32 + ch]);
        float sw = di * di;
        ax += vs.x * sw;
        ay += vs.y * sw;
    }
    float2 b = ((const float2*)bias)[ch];
    ax += b.x;
    ay += b.y;
    if (sub == 0) {
        ((float2*)out)[(size_t)wid * 32 + ch] = make_float2(ax, ay);
    }
}

// ---------------- launch ----------------

extern "C" void kernel_launch(void* const* d_in, const int* in_sizes, int n_in,
                              void* d_out, int out_size, void* d_ws, size_t ws_size,
                              hipStream_t stream) {
    const float* x  = (const float*)d_in[0];
    const int*   ei = (const int*)d_in[1];
    const float* W1 = (const float*)d_in[2];
    const float* b1 = (const float*)d_in[3];
    const float* W2 = (const float*)d_in[4];
    const float* b2 = (const float*)d_in[5];
    const float* W3 = (const float*)d_in[6];
    const float* b3 = (const float*)d_in[7];

    const int N = in_sizes[0] / 128;
    const int E = in_sizes[1] / 2;
    const int* row = ei;       // sources
    const int* col = ei + E;   // targets

    const int NB = (N + 127) >> 7;
    const int B1 = (E + CHUNK - 1) / CHUNK;
    const int NBB1 = NB * B1;

    char* p = (char*)d_ws;
    auto alloc = [&](size_t bytes) {
        char* r = p;
        p += (bytes + 255) & ~(size_t)255;
        return r;
    };
    int*    offs  = (int*)alloc((size_t)(N + 1) * 4);
    float*  dinv  = (float*)alloc((size_t)N * 4);
    int*    histG = (int*)alloc((size_t)NBB1 * 4);
    int*    bsum  = (int*)alloc(1024 * 4);
    int*    ebuf  = (int*)alloc((size_t)E * 4);
    int*    csr   = (int*)alloc((size_t)E * 4);
    __half* h16   = (__half*)alloc((size_t)N * 128 * 2);  // GEMM output (fp16)
    float*  hB    = (float*)alloc((size_t)N * 128 * 4);   // agg output (fp32)

    const int nsb = (NBB1 + 1023) / 1024;

    // CSR build
    hist_pass<<<B1, 256, 0, stream>>>(col, E, NB, B1, histG);
    scan_blocks<<<nsb, 256, 0, stream>>>(histG, NBB1, bsum);
    scan_single<<<1, 256, 0, stream>>>(bsum, nsb);
    add_bsum<<<(NBB1 + 255) / 256, 256, 0, stream>>>(histG, bsum, NBB1);
    scatter_pass<<<B1, 256, 0, stream>>>(row, col, E, NB, B1, histG, ebuf);
    build_csr<<<NB, 256, 0, stream>>>(ebuf, histG, NB, B1, N, E, offs, dinv, csr);

    const int gGemm = (N + 127) / 128;
    const int gAgg = (N + 3) / 4;

    // layer 1: h = relu(S (x W1) + b1)
    gemm_fp32_h<128><<<gGemm, 256, 0, stream>>>(x, W1, h16, N);
    agg128<true><<<gAgg, 256, 0, stream>>>(h16, dinv, offs, csr, b1, hB, N);

    // layer 2
    gemm_fp32_h<128><<<gGemm, 256, 0, stream>>>(hB, W2, h16, N);
    agg128<true><<<gAgg, 256, 0, stream>>>(h16, dinv, offs, csr, b2, hB, N);

    // layer 3 (no relu), 64 cols
    gemm_fp32_h<64><<<gGemm, 256, 0, stream>>>(hB, W3, h16, N);
    agg64<<<gAgg, 256, 0, stream>>>(h16, dinv, offs, csr, b3, (float*)d_out, N);
}

// Round 4
// 286.112 us; speedup vs baseline: 2.4668x; 1.3579x over previous
//
#include <hip/hip_runtime.h>
#include <hip/hip_fp16.h>

// GCN 3-layer encoder.
// - CSR build: 2-level counting sort (no global atomics).
// - GEMM: fp16 MFMA (16x16x32), swapped operands (A=W^T from LDS, B=h rows from
//   global), fp32 accumulate, epilogue scales by dinv[row] -> h_pre fp16.
// - Aggregation: out[i] = di*(sum_e h_pre[src] + h_pre[i]) + b  (norm folded into h_pre).
//   Quarter-wave (16 lanes x float4) per edge: one full 256B row per edge fetch.

#define K_DIM 128
#define CHUNK 8192
#define NBMAX 1024  // supports N <= 131072

typedef _Float16 f16x8 __attribute__((ext_vector_type(8)));
typedef float f32x4 __attribute__((ext_vector_type(4)));

// ---------------- preprocessing: counting-sort CSR build ----------------

__global__ __launch_bounds__(256) void hist_pass(const int* __restrict__ col, int E,
                                                 int NB, int B1, int* __restrict__ histG) {
    __shared__ int h[NBMAX];
    const int tid = threadIdx.x;
    for (int i = tid; i < NB; i += 256) h[i] = 0;
    __syncthreads();
    const int base = blockIdx.x * CHUNK;
    const int end = min(base + CHUNK, E);
    for (int e = base + tid; e < end; e += 256) atomicAdd(&h[col[e] >> 7], 1);
    __syncthreads();
    for (int i = tid; i < NB; i += 256) histG[(size_t)i * B1 + blockIdx.x] = h[i];
}

__global__ __launch_bounds__(256) void scan_blocks(int* __restrict__ data, int n,
                                                   int* __restrict__ bsum) {
    __shared__ int sh[256];
    const int tid = threadIdx.x;
    const int base = blockIdx.x * 1024;
    int v[4];
    int sum = 0;
#pragma unroll
    for (int j = 0; j < 4; ++j) {
        int i = base + tid * 4 + j;
        v[j] = (i < n) ? data[i] : 0;
        sum += v[j];
    }
    sh[tid] = sum;
    __syncthreads();
#pragma unroll
    for (int off = 1; off < 256; off <<= 1) {
        int t = (tid >= off) ? sh[tid - off] : 0;
        __syncthreads();
        sh[tid] += t;
        __syncthreads();
    }
    int run = (tid > 0) ? sh[tid - 1] : 0;
#pragma unroll
    for (int j = 0; j < 4; ++j) {
        int i = base + tid * 4 + j;
        if (i < n) data[i] = run;
        run += v[j];
    }
    if (tid == 255) bsum[blockIdx.x] = sh[255];
}

__global__ __launch_bounds__(256) void scan_single(int* __restrict__ data, int n) {
    __shared__ int sh[256];
    const int tid = threadIdx.x;
    int v[4];
    int sum = 0;
#pragma unroll
    for (int j = 0; j < 4; ++j) {
        int i = tid * 4 + j;
        v[j] = (i < n) ? data[i] : 0;
        sum += v[j];
    }
    sh[tid] = sum;
    __syncthreads();
#pragma unroll
    for (int off = 1; off < 256; off <<= 1) {
        int t = (tid >= off) ? sh[tid - off] : 0;
        __syncthreads();
        sh[tid] += t;
        __syncthreads();
    }
    int run = (tid > 0) ? sh[tid - 1] : 0;
#pragma unroll
    for (int j = 0; j < 4; ++j) {
        int i = tid * 4 + j;
        if (i < n) data[i] = run;
        run += v[j];
    }
}

__global__ void add_bsum(int* __restrict__ data, const int* __restrict__ bsum, int n) {
    int i = blockIdx.x * 256 + threadIdx.x;
    if (i < n) data[i] += bsum[i >> 10];
}

__global__ __launch_bounds__(256) void scatter_pass(const int* __restrict__ row,
                                                    const int* __restrict__ col, int E,
                                                    int NB, int B1,
                                                    const int* __restrict__ histG,
                                                    int* __restrict__ ebuf) {
    __shared__ int cur[NBMAX];
    const int tid = threadIdx.x;
    for (int i = tid; i < NB; i += 256) cur[i] = histG[(size_t)i * B1 + blockIdx.x];
    __syncthreads();
    const int base = blockIdx.x * CHUNK;
    const int end = min(base + CHUNK, E);
    for (int e = base + tid; e < end; e += 256) {
        int d = col[e];
        int s = row[e];
        int pos = atomicAdd(&cur[d >> 7], 1);
        ebuf[pos] = (s << 7) | (d & 127);
    }
}

__global__ __launch_bounds__(256) void build_csr(const int* __restrict__ ebuf,
                                                 const int* __restrict__ histG,
                                                 int NB, int B1, int N, int E,
                                                 int* __restrict__ offs,
                                                 float* __restrict__ dinv,
                                                 int* __restrict__ csr) {
    __shared__ int cnt[128];
    __shared__ int scn[128];
    __shared__ int curL[128];
    const int tid = threadIdx.x;
    const int b = blockIdx.x;
    const int S = histG[(size_t)b * B1];
    const int T = (b + 1 < NB) ? histG[(size_t)(b + 1) * B1] : E;

    if (tid < 128) cnt[tid] = 0;
    __syncthreads();
    for (int i = S + tid; i < T; i += 256) atomicAdd(&cnt[ebuf[i] & 127], 1);
    __syncthreads();
    if (tid < 128) scn[tid] = cnt[tid];
    __syncthreads();
#pragma unroll
    for (int off = 1; off < 128; off <<= 1) {
        int t = (tid < 128 && tid >= off) ? scn[tid - off] : 0;
        __syncthreads();
        if (tid < 128) scn[tid] += t;
        __syncthreads();
    }
    if (tid < 128) {
        int exc = (tid > 0) ? scn[tid - 1] : 0;
        int node = b * 128 + tid;
        if (node < N) {
            offs[node] = S + exc;
            dinv[node] = rsqrtf((float)(cnt[tid] + 1));
        }
        curL[tid] = S + exc;
    }
    if (b == 0 && tid == 0) offs[N] = E;
    __syncthreads();
    for (int i = S + tid; i < T; i += 256) {
        int p = ebuf[i];
        int pos = atomicAdd(&curL[p & 127], 1);
        csr[pos] = p >> 7;
    }
}

// ---------------- fp16 casts ----------------

// x fp32 [N*128] -> x16 fp16, 8 elems/thread
__global__ void cast_x(const float* __restrict__ x, __half* __restrict__ x16, int n8) {
    int i = blockIdx.x * 256 + threadIdx.x;
    if (i >= n8) return;
    float4 v0 = ((const float4*)x)[2 * i];
    float4 v1 = ((const float4*)x)[2 * i + 1];
    __half2 o[4] = {__float22half2_rn(make_float2(v0.x, v0.y)),
                    __float22half2_rn(make_float2(v0.z, v0.w)),
                    __float22half2_rn(make_float2(v1.x, v1.y)),
                    __float22half2_rn(make_float2(v1.z, v1.w))};
    ((float4*)x16)[i] = *(float4*)o;
}

// W[k][nc] fp32 -> wT[n*128 + k] fp16 (transposed), all three weights
__global__ void prep_wT(const float* __restrict__ W1, const float* __restrict__ W2,
                        const float* __restrict__ W3, __half* __restrict__ wT1,
                        __half* __restrict__ wT2, __half* __restrict__ wT3) {
    int tid = blockIdx.x * 256 + threadIdx.x;
    if (tid < 16384) {
        int n = tid >> 7, k = tid & 127;
        wT1[tid] = __float2half(W1[k * 128 + n]);
    } else if (tid < 32768) {
        int t = tid - 16384;
        int n = t >> 7, k = t & 127;
        wT2[t] = __float2half(W2[k * 128 + n]);
    } else if (tid < 40960) {
        int t = tid - 32768;
        int n = t >> 7, k = t & 127;  // n in [0,64)
        wT3[t] = __float2half(W3[k * 64 + n]);
    }
}

// ------------- MFMA GEMM: out[m][n] = (A[m][:] @ W[:][n]) * dinv[m], fp16 out -------------
// Swapped operands: MFMA A-operand = W^T tile (LDS), B-operand = A rows (global).
// D[n-as-row][m-as-col] => lane holds m=l&15, n=(l>>4)*4+reg -> contiguous n at fixed m.

template <int NCOLS>
__global__ __launch_bounds__(256) void gemm_f16(const __half* __restrict__ A,   // [M][128]
                                                const __half* __restrict__ wT,  // [NCOLS][128]
                                                const float* __restrict__ dinv,
                                                __half* __restrict__ out, int M) {
    constexpr int NT = NCOLS / 16;  // 8 or 4
    __shared__ __half sWT[NCOLS][136];  // pad +8 halves: balanced b128 reads

    const int tid = threadIdx.x;
    // stage W^T into LDS (16B chunks)
    for (int idx = tid; idx < NCOLS * 16; idx += 256) {
        int n = idx >> 4, kc = (idx & 15) * 8;
        *(float4*)&sWT[n][kc] = *(const float4*)&wT[n * 128 + kc];
    }
    __syncthreads();

    const int wave = tid >> 6;
    const int l = tid & 63;
    const int lm = l & 15;   // m within 16-tile (also n-row for A frag)
    const int kg = l >> 4;   // k-group 0..3
    const int row0 = blockIdx.x * 128 + wave * 32;

    f32x4 acc[2][NT];
#pragma unroll
    for (int mt = 0; mt < 2; ++mt)
#pragma unroll
        for (int nt = 0; nt < NT; ++nt) acc[mt][nt] = {0.f, 0.f, 0.f, 0.f};

    const int m0 = row0 + lm;
    const int m1 = row0 + 16 + lm;
    const int mc0 = min(m0, M - 1);
    const int mc1 = min(m1, M - 1);

#pragma unroll
    for (int ks = 0; ks < 4; ++ks) {
        const int k0 = ks * 32 + kg * 8;
        f16x8 b0 = *(const f16x8*)&A[(size_t)mc0 * 128 + k0];
        f16x8 b1 = *(const f16x8*)&A[(size_t)mc1 * 128 + k0];
#pragma unroll
        for (int nt = 0; nt < NT; ++nt) {
            f16x8 a = *(const f16x8*)&sWT[nt * 16 + lm][k0];
            acc[0][nt] = __builtin_amdgcn_mfma_f32_16x16x32_f16(a, b0, acc[0][nt], 0, 0, 0);
            acc[1][nt] = __builtin_amdgcn_mfma_f32_16x16x32_f16(a, b1, acc[1][nt], 0, 0, 0);
        }
    }

    // epilogue: lane l, tile (mt,nt): m = row0+mt*16+lm, n = nt*16 + kg*4 + r
#pragma unroll
    for (int mt = 0; mt < 2; ++mt) {
        const int m = (mt == 0) ? m0 : m1;
        if (m < M) {
            const float dv = dinv[m];
#pragma unroll
            for (int nt = 0; nt < NT; ++nt) {
                float z0 = acc[mt][nt][0] * dv, z1 = acc[mt][nt][1] * dv;
                float z2 = acc[mt][nt][2] * dv, z3 = acc[mt][nt][3] * dv;
                __half2 o[2] = {__float22half2_rn(make_float2(z0, z1)),
                                __float22half2_rn(make_float2(z2, z3))};
                *(float2*)&out[(size_t)m * NCOLS + nt * 16 + kg * 4] = *(float2*)o;
            }
        }
    }
}

// ------------- aggregation: quarter-wave float4 gather, norm pre-folded -------------
// C=128: 16 lanes x 16B = full row per edge; 4 edge slots/wave.

template <bool RELU>
__global__ __launch_bounds__(256) void agg128(const __half* __restrict__ h,  // h_pre [N][128]
                                              const float* __restrict__ dinv,
                                              const int* __restrict__ offs,
                                              const int* __restrict__ csr,
                                              const float* __restrict__ bias,
                                              __half* __restrict__ out, int N) {
    const int wid = (blockIdx.x * 256 + threadIdx.x) >> 6;
    if (wid >= N) return;
    const int l = threadIdx.x & 63;
    const int q = l >> 4;  // edge slot
    const int c = l & 15;  // 16B chunk (8 channels)
    const int beg = offs[wid], end = offs[wid + 1];
    const float di = dinv[wid];
    const float4* __restrict__ hp = (const float4*)h;  // row = 16 float4

    float a[8] = {0.f, 0.f, 0.f, 0.f, 0.f, 0.f, 0.f, 0.f};
    if (beg < end) {
        const int last = end - 1;
        for (int e = beg; e < end; e += 8) {
            int i0 = e + q, i1 = e + 4 + q;
            float m0 = (i0 < end) ? 1.f : 0.f;
            float m1 = (i1 < end) ? 1.f : 0.f;
            int s0 = csr[min(i0, last)];
            int s1 = csr[min(i1, last)];
            float4 r0 = hp[(size_t)s0 * 16 + c];
            float4 r1 = hp[(size_t)s1 * 16 + c];
            const __half2* h0 = (const __half2*)&r0;
            const __half2* h1 = (const __half2*)&r1;
#pragma unroll
            for (int j = 0; j < 4; ++j) {
                float2 f0 = __half22float2(h0[j]);
                float2 f1 = __half22float2(h1[j]);
                a[2 * j] = fmaf(f0.x, m0, a[2 * j]);
                a[2 * j + 1] = fmaf(f0.y, m0, a[2 * j + 1]);
                a[2 * j] = fmaf(f1.x, m1, a[2 * j]);
                a[2 * j + 1] = fmaf(f1.y, m1, a[2 * j + 1]);
            }
        }
    }
#pragma unroll
    for (int j = 0; j < 8; ++j) {
        a[j] += __shfl_xor(a[j], 16);
        a[j] += __shfl_xor(a[j], 32);
    }
    {  // self-loop: + h_pre[wid]
        float4 rs = hp[(size_t)wid * 16 + c];
        const __half2* hs = (const __half2*)&rs;
#pragma unroll
        for (int j = 0; j < 4; ++j) {
            float2 f = __half22float2(hs[j]);
            a[2 * j] += f.x;
            a[2 * j + 1] += f.y;
        }
    }
    float4 b0 = ((const float4*)bias)[2 * c];
    float4 b1 = ((const float4*)bias)[2 * c + 1];
    float z[8];
    z[0] = fmaf(di, a[0], b0.x); z[1] = fmaf(di, a[1], b0.y);
    z[2] = fmaf(di, a[2], b0.z); z[3] = fmaf(di, a[3], b0.w);
    z[4] = fmaf(di, a[4], b1.x); z[5] = fmaf(di, a[5], b1.y);
    z[6] = fmaf(di, a[6], b1.z); z[7] = fmaf(di, a[7], b1.w);
    if (RELU) {
#pragma unroll
        for (int j = 0; j < 8; ++j) z[j] = fmaxf(z[j], 0.f);
    }
    if (q == 0) {
        __half2 o[4] = {__float22half2_rn(make_float2(z[0], z[1])),
                        __float22half2_rn(make_float2(z[2], z[3])),
                        __float22half2_rn(make_float2(z[4], z[5])),
                        __float22half2_rn(make_float2(z[6], z[7]))};
        ((float4*)out)[(size_t)wid * 16 + c] = *(float4*)o;
    }
}

// C=64: 8 lanes x 16B = full row per edge; 8 edge slots/wave. fp32 output.
__global__ __launch_bounds__(256) void agg64(const __half* __restrict__ h,  // [N][64]
                                             const float* __restrict__ dinv,
                                             const int* __restrict__ offs,
                                             const int* __restrict__ csr,
                                             const float* __restrict__ bias,
                                             float* __restrict__ out, int N) {
    const int wid = (blockIdx.x * 256 + threadIdx.x) >> 6;
    if (wid >= N) return;
    const int l = threadIdx.x & 63;
    const int q = l >> 3;  // edge slot 0..7
    const int c = l & 7;   // 16B chunk (8 channels)
    const int beg = offs[wid], end = offs[wid + 1];
    const float di = dinv[wid];
    const float4* __restrict__ hp = (const float4*)h;  // row = 8 float4

    float a[8] = {0.f, 0.f, 0.f, 0.f, 0.f, 0.f, 0.f, 0.f};
    if (beg < end) {
        const int last = end - 1;
        for (int e = beg; e < end; e += 8) {
            int i0 = e + q;
            float m0 = (i0 < end) ? 1.f : 0.f;
            int s0 = csr[min(i0, last)];
            float4 r0 = hp[(size_t)s0 * 8 + c];
            const __half2* h0 = (const __half2*)&r0;
#pragma unroll
            for (int j = 0; j < 4; ++j) {
                float2 f0 = __half22float2(h0[j]);
                a[2 * j] = fmaf(f0.x, m0, a[2 * j]);
                a[2 * j + 1] = fmaf(f0.y, m0, a[2 * j + 1]);
            }
        }
    }
#pragma unroll
    for (int j = 0; j < 8; ++j) {
        a[j] += __shfl_xor(a[j], 8);
        a[j] += __shfl_xor(a[j], 16);
        a[j] += __shfl_xor(a[j], 32);
    }
    {
        float4 rs = hp[(size_t)wid * 8 + c];
        const __half2* hs = (const __half2*)&rs;
#pragma unroll
        for (int j = 0; j < 4; ++j) {
            float2 f = __half22float2(hs[j]);
            a[2 * j] += f.x;
            a[2 * j + 1] += f.y;
        }
    }
    float4 b0 = ((const float4*)bias)[2 * c];
    float4 b1 = ((const float4*)bias)[2 * c + 1];
    float z[8];
    z[0] = fmaf(di, a[0], b0.x); z[1] = fmaf(di, a[1], b0.y);
    z[2] = fmaf(di, a[2], b0.z); z[3] = fmaf(di, a[3], b0.w);
    z[4] = fmaf(di, a[4], b1.x); z[5] = fmaf(di, a[5], b1.y);
    z[6] = fmaf(di, a[6], b1.z); z[7] = fmaf(di, a[7], b1.w);
    if (q == 0) {
        ((float4*)out)[(size_t)wid * 16 + 2 * c] = make_float4(z[0], z[1], z[2], z[3]);
        ((float4*)out)[(size_t)wid * 16 + 2 * c + 1] = make_float4(z[4], z[5], z[6], z[7]);
    }
}

// ---------------- launch ----------------

extern "C" void kernel_launch(void* const* d_in, const int* in_sizes, int n_in,
                              void* d_out, int out_size, void* d_ws, size_t ws_size,
                              hipStream_t stream) {
    const float* x  = (const float*)d_in[0];
    const int*   ei = (const int*)d_in[1];
    const float* W1 = (const float*)d_in[2];
    const float* b1 = (const float*)d_in[3];
    const float* W2 = (const float*)d_in[4];
    const float* b2 = (const float*)d_in[5];
    const float* W3 = (const float*)d_in[6];
    const float* b3 = (const float*)d_in[7];

    const int N = in_sizes[0] / 128;
    const int E = in_sizes[1] / 2;
    const int* row = ei;       // sources
    const int* col = ei + E;   // targets

    const int NB = (N + 127) >> 7;
    const int B1 = (E + CHUNK - 1) / CHUNK;
    const int NBB1 = NB * B1;

    char* p = (char*)d_ws;
    auto alloc = [&](size_t bytes) {
        char* r = p;
        p += (bytes + 255) & ~(size_t)255;
        return r;
    };
    int*    offs  = (int*)alloc((size_t)(N + 1) * 4);
    float*  dinv  = (float*)alloc((size_t)N * 4);
    int*    histG = (int*)alloc((size_t)NBB1 * 4);
    int*    bsum  = (int*)alloc(1024 * 4);
    int*    ebuf  = (int*)alloc((size_t)E * 4);
    int*    csr   = (int*)alloc((size_t)E * 4);
    __half* bufA  = (__half*)alloc((size_t)N * 128 * 2);  // GEMM out (h_pre)
    __half* bufB  = (__half*)alloc((size_t)N * 128 * 2);  // x16 / agg out
    __half* wT1   = (__half*)alloc(16384 * 2);
    __half* wT2   = (__half*)alloc(16384 * 2);
    __half* wT3   = (__half*)alloc(8192 * 2);

    const int nsb = (NBB1 + 1023) / 1024;

    // CSR build (produces dinv used by GEMM epilogues)
    hist_pass<<<B1, 256, 0, stream>>>(col, E, NB, B1, histG);
    scan_blocks<<<nsb, 256, 0, stream>>>(histG, NBB1, bsum);
    scan_single<<<1, 256, 0, stream>>>(bsum, nsb);
    add_bsum<<<(NBB1 + 255) / 256, 256, 0, stream>>>(histG, bsum, NBB1);
    scatter_pass<<<B1, 256, 0, stream>>>(row, col, E, NB, B1, histG, ebuf);
    build_csr<<<NB, 256, 0, stream>>>(ebuf, histG, NB, B1, N, E, offs, dinv, csr);

    // fp16 prep
    const int n8 = N * 128 / 8;
    cast_x<<<(n8 + 255) / 256, 256, 0, stream>>>(x, bufB, n8);
    prep_wT<<<160, 256, 0, stream>>>(W1, W2, W3, wT1, wT2, wT3);

    const int gGemm = (N + 127) / 128;
    const int gAgg = (N + 3) / 4;

    // layer 1
    gemm_f16<128><<<gGemm, 256, 0, stream>>>(bufB, wT1, dinv, bufA, N);
    agg128<true><<<gAgg, 256, 0, stream>>>(bufA, dinv, offs, csr, b1, bufB, N);

    // layer 2
    gemm_f16<128><<<gGemm, 256, 0, stream>>>(bufB, wT2, dinv, bufA, N);
    agg128<true><<<gAgg, 256, 0, stream>>>(bufA, dinv, offs, csr, b2, bufB, N);

    // layer 3 (64 cols, no relu, fp32 out)
    gemm_f16<64><<<gGemm, 256, 0, stream>>>(bufB, wT3, dinv, bufA, N);
    agg64<<<gAgg, 256, 0, stream>>>(bufA, dinv, offs, csr, b3, (float*)d_out, N);
}